// Round 10
// baseline (10276.904 us; speedup 1.0000x reference)
//
#include <hip/hip_runtime.h>
#include <cstddef>
#include <cstdint>

#define T_STEPS 256
#define BATCH   512
#define NIN     128
#define NHID    1024
#define NWGS    256

typedef _Float16 half8  __attribute__((ext_vector_type(8)));
typedef float    float4v __attribute__((ext_vector_type(4)));

__device__ __forceinline__ float sigmoid_f(float x) { return 1.0f / (1.0f + __expf(-x)); }
__device__ __forceinline__ float tanh_f(float x) {
    float ax = fabsf(x);
    float t  = __expf(-2.0f * ax);
    float r  = (1.0f - t) / (1.0f + t);
    return copysignf(r, x);
}

// LDS map (dynamic, ~152.2 KB)
#define WLDS_OFF  0         // 131072 B: weight B-frags [nt 2][kt 64][lane 64][16B]
#define WHF_OFF   131072    // 4096 B : proj B-frags [kt 4][lane 64][16B]
#define RED_OFF   135168    // 16384 B: k-half reduction [mw 8][nt 2][r 4][lane 64] f32
#define HS_OFF    151552    // 4096 B : per-wave h transpose (16 x 256B)
#define BIASG_OFF 155648    // 128 B  : gate bias [g 4][u 8] f32
#define BH_OFF    155776    // 32 B   : proj bias [u 8] f32
#define SMEM_BYTES 155840

// ---------------------------------------------------------------------------
// Grid barrier (agent scope) — proven in R8/R9.
// ---------------------------------------------------------------------------
__device__ __forceinline__ void grid_barrier(uint32_t* cnt, uint32_t* gen,
                                             uint32_t target_gen) {
    __syncthreads();
    if (threadIdx.x == 0) {
        __threadfence();
        uint32_t old = __hip_atomic_fetch_add(cnt, 1u, __ATOMIC_RELAXED,
                                              __HIP_MEMORY_SCOPE_AGENT);
        if (old == target_gen * NWGS - 1)
            __hip_atomic_store(gen, target_gen, __ATOMIC_RELAXED,
                               __HIP_MEMORY_SCOPE_AGENT);
        uint32_t spins = 0;
        while (__hip_atomic_load(gen, __ATOMIC_RELAXED,
                                 __HIP_MEMORY_SCOPE_AGENT) < target_gen) {
            __builtin_amdgcn_s_sleep(8);
            if (++spins > 20000000u) break;
        }
        __threadfence();
    }
    __syncthreads();
}

// ---------------------------------------------------------------------------
// One-time x -> fp16 A-frag conversion (unchanged from R9).
// xf[t 256][mt 32][kt 4][512]; val = x[mt*16+(lane&15)][t][kt*32+(lane>>4)*8+j]
// ---------------------------------------------------------------------------
__global__ __launch_bounds__(256)
void xconv_kernel(const float* __restrict__ x, _Float16* __restrict__ xf)
{
    __shared__ float xs[16][2][128];
    const int mt = blockIdx.x, tb = blockIdx.y;
    const int t = threadIdx.x;
    for (int tl = 0; tl < 8; ++tl) {
        __syncthreads();
#pragma unroll
        for (int i = 0; i < 4; ++i) {
            const int idx = t + i * 256;
            const int m = idx >> 6, rest = idx & 63;
            const int t2 = rest >> 5, k4 = rest & 31;
            float4v v = *(const float4v*)(x +
                ((size_t)(mt * 16 + m) * T_STEPS + (tb * 16 + tl * 2 + t2)) * NIN + k4 * 4);
            *(float4v*)&xs[m][t2][k4 * 4] = v;
        }
        __syncthreads();
#pragma unroll
        for (int i = 0; i < 2; ++i) {
            const int idx = t + i * 256;
            const int t2 = idx >> 8, rest = idx & 255;
            const int kt = rest >> 6, lane = rest & 63;
            half8 hv;
#pragma unroll
            for (int j = 0; j < 8; ++j)
                hv[j] = (_Float16)xs[lane & 15][t2][kt * 32 + (lane >> 4) * 8 + j];
            const int tg = tb * 16 + tl * 2 + t2;
            *(half8*)(xf + (((size_t)tg * 32 + mt) * 4 + kt) * 512 + lane * 8) = hv;
        }
    }
}

// ---------------------------------------------------------------------------
// Persistent kernel.  256 WGs x 1024 thr (16 waves), 1 WG/CU (152 KB LDS).
// WG: layer = bid&1, slice s = bid>>1; owns N=32 cols (4 gates x 8 units).
// Waves: mw = w&7 (m-group, 4 mt each -> M=512), kh = w>>3 (K-half).
// Weights fp16 LDS-pinned; c-state in VGPRs for the whole sequence.
// Epilogue: gate exchange via shfl_xor(8) — no LDS scratch, no conflicts.
// ---------------------------------------------------------------------------
__global__ __launch_bounds__(1024, 4)
void persist_kernel(const float* __restrict__ k1, const float* __restrict__ b1,
                    const float* __restrict__ k2, const float* __restrict__ b2,
                    const float* __restrict__ W_h, const float* __restrict__ b_h,
                    const _Float16* __restrict__ xf,
                    uint8_t* wsb, float* __restrict__ out,
                    uint32_t* barrier_mem)
{
    extern __shared__ __align__(16) char smem[];
    const size_t MB = 1024 * 1024;
    _Float16* A1b[2] = {(_Float16*)(wsb + 0 * MB), (_Float16*)(wsb + 2 * MB)};
    _Float16* A2b[2] = {(_Float16*)(wsb + 4 * MB), (_Float16*)(wsb + 6 * MB)};
    uint32_t* cnt = barrier_mem;
    uint32_t* gen = barrier_mem + 32;

    const int tid = threadIdx.x;
    const int w = tid >> 6, lane = tid & 63;
    const int mw = w & 7, kh = w >> 3;
    const int q = lane >> 4, n16 = lane & 15;
    const int bid = blockIdx.x;
    const int layer = bid & 1;
    const int s = bid >> 1;          // 0..127
    const int u0 = s * 8;

    const float* ksrc = layer ? k2 : k1;
    const float* bsrc = layer ? b2 : b1;

    // ---- init: weight slice f32 -> fp16 frags in LDS (one-time) ----
#pragma unroll 1
    for (int i = 0; i < 8; ++i) {
        const int f  = w * 8 + i;           // 0..127
        const int nt = f >> 6, kt = f & 63;
        const int colg = (nt * 2 + (n16 >> 3)) * 1024 + u0 + (n16 & 7);
        half8 hv;
#pragma unroll
        for (int j = 0; j < 8; ++j)
            hv[j] = (_Float16)ksrc[(size_t)(kt * 32 + q * 8 + j) * 4096 + colg];
        *(half8*)(smem + WLDS_OFF + (nt * 64 + kt) * 1024 + lane * 16) = hv;
    }
    if (tid < 32)
        ((float*)(smem + BIASG_OFF))[tid] = bsrc[(tid >> 3) * 1024 + u0 + (tid & 7)];
    if (layer == 0) {
        if (tid < 256) {
            const int kt = tid >> 6, ln = tid & 63;
            const int nn = ln & 15;
            half8 hv;
#pragma unroll
            for (int j = 0; j < 8; ++j) {
                float v = (nn < 8)
                    ? W_h[(size_t)(kt * 32 + (ln >> 4) * 8 + j) * NHID + u0 + nn] : 0.f;
                hv[j] = (_Float16)v;
            }
            *(half8*)(smem + WHF_OFF + kt * 1024 + ln * 16) = hv;
        }
        if (tid < 8) ((float*)(smem + BH_OFF))[tid] = b_h[u0 + tid];
    }
    __syncthreads();

    const float* bg = (const float*)(smem + BIASG_OFF);
    const float* bh = (const float*)(smem + BH_OFF);
    _Float16* hw = (_Float16*)(smem + HS_OFF + w * 256);   // [16 rows][8 u]

    // c-state: kh==0, lanes n16<8: rows q*4+r, unit u0+n16, per mt
    float cst[4][4];
#pragma unroll
    for (int mt = 0; mt < 4; ++mt)
#pragma unroll
        for (int r = 0; r < 4; ++r) cst[mt][r] = 0.f;

    // ---- proj body (layer-0 WGs): relu(x_t @ W + b) -> A1dst low half ----
    auto proj_step = [&](int tstep, _Float16* A1dst) {
#pragma unroll 1
        for (int i = 0; i < 2; ++i) {
            const int mtp = w * 2 + i;      // 0..31
            float4v pacc = (float4v){0.f, 0.f, 0.f, 0.f};
#pragma unroll
            for (int kt = 0; kt < 4; ++kt) {
                half8 B = *(const half8*)(smem + WHF_OFF + kt * 1024 + lane * 16);
                half8 A = *(const half8*)(xf +
                    (((size_t)tstep * 32 + mtp) * 4 + kt) * 512 + lane * 8);
                pacc = __builtin_amdgcn_mfma_f32_16x16x32_f16(A, B, pacc, 0, 0, 0);
            }
            if (n16 < 8) {
#pragma unroll
                for (int r = 0; r < 4; ++r)
                    hw[(q * 4 + r) * 8 + n16] =
                        (_Float16)fmaxf(pacc[r] + bh[n16], 0.f);
            }
            if (lane < 16) {
                half8 hv = *(half8*)(hw + lane * 8);
                *(half8*)(A1dst + ((size_t)mtp * 64 + (s >> 2)) * 512
                                + ((s & 3) * 16 + lane) * 8) = hv;
            }
        }
    };

    // ---- LSTM GEMM + fused epilogue ----
    auto gemm_step = [&](const _Float16* Asrc, _Float16* hdst1, _Float16* hdst2,
                         float* outp) {
        float4v acc[4][2];
#pragma unroll
        for (int mt = 0; mt < 4; ++mt) {
            acc[mt][0] = (float4v){0.f, 0.f, 0.f, 0.f};
            acc[mt][1] = (float4v){0.f, 0.f, 0.f, 0.f};
        }
        const char* aw[4];
#pragma unroll
        for (int mt = 0; mt < 4; ++mt)
            aw[mt] = (const char*)Asrc
                   + ((size_t)((mw * 4 + mt) * 64 + kh * 32)) * 1024 + lane * 16;

        half8 Ab[2][4];
#pragma unroll
        for (int mt = 0; mt < 4; ++mt) Ab[0][mt] = *(const half8*)(aw[mt]);
#pragma unroll 2
        for (int kt2 = 0; kt2 < 32; ++kt2) {
            const int cur = kt2 & 1;
            if (kt2 < 31) {
#pragma unroll
                for (int mt = 0; mt < 4; ++mt)
                    Ab[cur ^ 1][mt] = *(const half8*)(aw[mt] + (size_t)(kt2 + 1) * 1024);
            }
            const int kt = kh * 32 + kt2;
            half8 B0 = *(const half8*)(smem + WLDS_OFF + kt * 1024 + lane * 16);
            half8 B1 = *(const half8*)(smem + WLDS_OFF + 65536 + kt * 1024 + lane * 16);
#pragma unroll
            for (int mt = 0; mt < 4; ++mt)
                acc[mt][0] = __builtin_amdgcn_mfma_f32_16x16x32_f16(Ab[cur][mt], B0, acc[mt][0], 0, 0, 0);
#pragma unroll
            for (int mt = 0; mt < 4; ++mt)
                acc[mt][1] = __builtin_amdgcn_mfma_f32_16x16x32_f16(Ab[cur][mt], B1, acc[mt][1], 0, 0, 0);
        }

        // k-half reduction (4 mt-passes through 16 KB LDS)
        float* red = (float*)(smem + RED_OFF);
#pragma unroll 1
        for (int mt = 0; mt < 4; ++mt) {
            __syncthreads();
            if (kh == 1) {
#pragma unroll
                for (int nt = 0; nt < 2; ++nt)
#pragma unroll
                    for (int r = 0; r < 4; ++r)
                        red[(mw * 8 + nt * 4 + r) * 64 + lane] = acc[mt][nt][r];
            }
            __syncthreads();
            if (kh == 0) {
#pragma unroll
                for (int nt = 0; nt < 2; ++nt)
#pragma unroll
                    for (int r = 0; r < 4; ++r)
                        acc[mt][nt][r] += red[(mw * 8 + nt * 4 + r) * 64 + lane];
            }
        }

        // epilogue (kh==0 waves): gate exchange via shfl_xor(8), no LDS scratch
        if (kh == 0) {
#pragma unroll 1
            for (int mt = 0; mt < 4; ++mt) {
                float zi[4], zj[4], zf[4], zo[4];
#pragma unroll
                for (int r = 0; r < 4; ++r) {
                    const float a0 = acc[mt][0][r];
                    const float a1 = acc[mt][1][r];
                    zj[r] = __shfl_xor(a0, 8, 64);
                    zo[r] = __shfl_xor(a1, 8, 64);
                    zi[r] = a0;
                    zf[r] = a1;
                }
                float hvals[4];
                if (n16 < 8) {
                    const float bi = bg[n16],      bj = bg[8 + n16];
                    const float bf = bg[16 + n16], bo = bg[24 + n16];
#pragma unroll
                    for (int r = 0; r < 4; ++r) {
                        float c = cst[mt][r] * sigmoid_f(zf[r] + bf + 1.0f)
                                + sigmoid_f(zi[r] + bi) * tanh_f(zj[r] + bj);
                        cst[mt][r] = c;
                        hvals[r] = tanh_f(c) * sigmoid_f(zo[r] + bo);
                        hw[(q * 4 + r) * 8 + n16] = (_Float16)hvals[r];
                    }
                    if (outp) {
#pragma unroll
                        for (int r = 0; r < 4; ++r)
                            outp[(size_t)((mw * 4 + mt) * 16 + q * 4 + r) * NHID
                                 + u0 + n16] = hvals[r];
                    }
                }
                if (lane < 16) {
                    half8 hv = *(half8*)(hw + lane * 8);
                    const size_t loff = ((s & 3) * 16 + lane) * 8;
                    const int mtg = mw * 4 + mt;
                    *(half8*)(hdst1 + ((size_t)mtg * 64 + 32 + (s >> 2)) * 512 + loff) = hv;
                    if (hdst2)
                        *(half8*)(hdst2 + ((size_t)mtg * 64 + (s >> 2)) * 512 + loff) = hv;
                }
            }
        }
    };

    // ---- pre-phase: proj(0) -> A1[0].low ----
    if (layer == 0) proj_step(0, A1b[0]);
    grid_barrier(cnt, gen, 1u);

    // ---- phases ----
    for (int p = 0; p <= 256; ++p) {
        const int pi = p & 1, po = pi ^ 1;
        if (layer == 0) {
            if (p <= 255)
                gemm_step(A1b[pi], A1b[po], A2b[po], nullptr);   // h1 -> A1hi, A2lo
            if (p + 1 <= 255)
                proj_step(p + 1, A1b[po]);
        } else {
            if (p >= 1)
                gemm_step(A2b[pi], A2b[po], nullptr,
                          (p == 256) ? out : nullptr);           // h2 -> A2hi
        }
        grid_barrier(cnt, gen, (uint32_t)(p + 2));
    }
}

// ---------------------------------------------------------------------------
extern "C" void kernel_launch(void* const* d_in, const int* in_sizes, int n_in,
                              void* d_out, int out_size, void* d_ws, size_t ws_size,
                              hipStream_t stream)
{
    const float* x   = (const float*)d_in[0];
    const float* W_h = (const float*)d_in[1];
    const float* b_h = (const float*)d_in[2];
    const float* k1  = (const float*)d_in[3];
    const float* b1  = (const float*)d_in[4];
    const float* k2  = (const float*)d_in[5];
    const float* b2  = (const float*)d_in[6];
    float* out = (float*)d_out;

    const size_t MB = 1024 * 1024;
    uint8_t* wsb = (uint8_t*)d_ws;
    // A1[0] 0-2, A1[1] 2-4, A2[0] 4-6, A2[1] 6-8 MB ; xf 8-40 MB ; barrier @40 MB
    _Float16* xf = (_Float16*)(wsb + 8 * MB);
    uint32_t* barrier_mem = (uint32_t*)(wsb + 40 * MB);

    hipFuncSetAttribute((const void*)persist_kernel,
                        hipFuncAttributeMaxDynamicSharedMemorySize, SMEM_BYTES);

    hipMemsetAsync(wsb, 0, 8 * MB, stream);          // zero all A-buffers
    hipMemsetAsync(barrier_mem, 0, 4096, stream);
    xconv_kernel<<<dim3(32, 16), 256, 0, stream>>>(x, xf);
    persist_kernel<<<NWGS, 1024, SMEM_BYTES, stream>>>(
        k1, b1, k2, b2, W_h, b_h, xf, wsb, out, barrier_mem);
}